// Round 1
// baseline (899.896 us; speedup 1.0000x reference)
//
#include <hip/hip_runtime.h>
#include <hip/hip_bf16.h>
#include <math.h>

#define L_ 8
#define B_ 2
#define N_ 512
#define D_ 1024
#define H_ 8
#define DH_ 64
#define INNER_ 512
#define M_ 16
#define BN_TOK 1024            // B_*N_
#define EPS 1.1920928955078125e-07f
#define SCALE_ 0.125f          // DH^-0.5

// ---------------------------------------------------------------------------
// rs + gates kernel: one block per (l,b,n) row.
//   rs[row]    = rsqrt(mean(tokens_row^2) + eps)
//   gates[row] = sigmoid((tokens_row * rs * norm_w) @ wg)   [8 heads]
// ---------------------------------------------------------------------------
__global__ __launch_bounds__(256) void rs_gates_kernel(
    const float* __restrict__ tokens, const float* __restrict__ norm_w,
    const float* __restrict__ wg, float* __restrict__ rs_out,
    float* __restrict__ gates_out)
{
    const int row = blockIdx.x;               // l*1024 + b*512 + n
    const float* tr = tokens + (size_t)row * D_;
    const int t = threadIdx.x;
    const int wave = t >> 6, lane = t & 63;
    __shared__ float wsum[4];
    __shared__ float wacc[4][8];

    // pass 1: sum of squares
    float ss = 0.f;
    for (int d = t; d < D_; d += 256) { float v = tr[d]; ss = fmaf(v, v, ss); }
    #pragma unroll
    for (int o = 1; o < 64; o <<= 1) ss += __shfl_xor(ss, o);
    if (lane == 0) wsum[wave] = ss;
    __syncthreads();
    const float tot = wsum[0] + wsum[1] + wsum[2] + wsum[3];
    const float rsv = rsqrtf(tot * (1.f / D_) + EPS);
    if (t == 0) rs_out[row] = rsv;

    // pass 2: gates = sigmoid(tn @ wg)
    float acc[8];
    #pragma unroll
    for (int h = 0; h < 8; ++h) acc[h] = 0.f;
    for (int d = t; d < D_; d += 256) {
        float v = tr[d] * rsv * norm_w[d];
        const float* wrow = wg + (size_t)d * H_;
        #pragma unroll
        for (int h = 0; h < 8; ++h) acc[h] = fmaf(v, wrow[h], acc[h]);
    }
    #pragma unroll
    for (int h = 0; h < 8; ++h) {
        #pragma unroll
        for (int o = 1; o < 64; o <<= 1) acc[h] += __shfl_xor(acc[h], o);
    }
    if (lane == 0) {
        #pragma unroll
        for (int h = 0; h < 8; ++h) wacc[wave][h] = acc[h];
    }
    __syncthreads();
    if (t < 8) {
        float g = wacc[0][t] + wacc[1][t] + wacc[2][t] + wacc[3][t];
        gates_out[(size_t)row * H_ + t] = 1.f / (1.f + expf(-g));
    }
}

// ---------------------------------------------------------------------------
// NT batched GEMM (member linear): C[l] = A[l] @ W[l]^T + bias[l]
//   A [L,1024,1024] row-major, W [L,1024(o),1024(d)] row-major.
// 128x128x16 tile, 256 threads, 8x8 per thread.
// ---------------------------------------------------------------------------
__global__ __launch_bounds__(256) void gemm_nt_batched_kernel(
    const float* __restrict__ A, const float* __restrict__ W,
    const float* __restrict__ bias, float* __restrict__ C)
{
    const int l = blockIdx.z;
    const float* Al = A + (size_t)l * BN_TOK * D_;
    const float* Wl = W + (size_t)l * D_ * D_;
    float* Cl = C + (size_t)l * BN_TOK * D_;

    __shared__ __align__(16) float As[16][132];
    __shared__ __align__(16) float Ws[16][132];
    const int t = threadIdx.x;
    const int m0 = blockIdx.y * 128;
    const int n0 = blockIdx.x * 128;
    const int tx = t & 15, ty = t >> 4;

    float acc[8][8];
    #pragma unroll
    for (int i = 0; i < 8; ++i)
        #pragma unroll
        for (int j = 0; j < 8; ++j) acc[i][j] = 0.f;

    for (int k0 = 0; k0 < D_; k0 += 16) {
        #pragma unroll
        for (int r = 0; r < 2; ++r) {
            int q = t + r * 256;
            int row = q >> 2, c4 = q & 3;
            float4 va = *(const float4*)(Al + (size_t)(m0 + row) * D_ + k0 + c4 * 4);
            As[c4 * 4 + 0][row] = va.x; As[c4 * 4 + 1][row] = va.y;
            As[c4 * 4 + 2][row] = va.z; As[c4 * 4 + 3][row] = va.w;
            float4 vw = *(const float4*)(Wl + (size_t)(n0 + row) * D_ + k0 + c4 * 4);
            Ws[c4 * 4 + 0][row] = vw.x; Ws[c4 * 4 + 1][row] = vw.y;
            Ws[c4 * 4 + 2][row] = vw.z; Ws[c4 * 4 + 3][row] = vw.w;
        }
        __syncthreads();
        #pragma unroll
        for (int k = 0; k < 16; ++k) {
            float a[8], b[8];
            *(float4*)&a[0] = *(const float4*)&As[k][ty * 8];
            *(float4*)&a[4] = *(const float4*)&As[k][ty * 8 + 4];
            *(float4*)&b[0] = *(const float4*)&Ws[k][tx * 8];
            *(float4*)&b[4] = *(const float4*)&Ws[k][tx * 8 + 4];
            #pragma unroll
            for (int i = 0; i < 8; ++i)
                #pragma unroll
                for (int j = 0; j < 8; ++j) acc[i][j] = fmaf(a[i], b[j], acc[i][j]);
        }
        __syncthreads();
    }
    float bj[8];
    #pragma unroll
    for (int j = 0; j < 8; ++j) bj[j] = bias[(size_t)l * D_ + n0 + tx * 8 + j];
    #pragma unroll
    for (int i = 0; i < 8; ++i) {
        float* dst = Cl + (size_t)(m0 + ty * 8 + i) * D_ + n0 + tx * 8;
        float4 v0 = make_float4(acc[i][0] + bj[0], acc[i][1] + bj[1], acc[i][2] + bj[2], acc[i][3] + bj[3]);
        float4 v1 = make_float4(acc[i][4] + bj[4], acc[i][5] + bj[5], acc[i][6] + bj[6], acc[i][7] + bj[7]);
        *(float4*)dst = v0;
        *(float4*)(dst + 4) = v1;
    }
}

// ---------------------------------------------------------------------------
// NN GEMM: C = A' @ Bm.  AMODE: 0 plain; 1 rows scaled by rs[i]*norm_w[d];
// 2 ctx gather (rows [0,8K) from A=tokens, rows [8K,16K) from A2=out).
// 128x128x16 tile, 256 threads, 8x8 per thread.
// ---------------------------------------------------------------------------
template <int AMODE>
__global__ __launch_bounds__(256) void gemm_nn_kernel(
    const float* __restrict__ A, const float* __restrict__ A2,
    const float* __restrict__ Bm, float* __restrict__ C,
    const float* __restrict__ rs, const float* __restrict__ nw,
    int Mrows, int Ncols, int K)
{
    __shared__ __align__(16) float As[16][132];
    __shared__ __align__(16) float Bs[16][132];
    const int t = threadIdx.x;
    const int m0 = blockIdx.y * 128;
    const int n0 = blockIdx.x * 128;
    const int tx = t & 15, ty = t >> 4;

    float acc[8][8];
    #pragma unroll
    for (int i = 0; i < 8; ++i)
        #pragma unroll
        for (int j = 0; j < 8; ++j) acc[i][j] = 0.f;

    for (int k0 = 0; k0 < K; k0 += 16) {
        #pragma unroll
        for (int r = 0; r < 2; ++r) {
            int q = t + r * 256;
            int row = q >> 2, c4 = q & 3;
            int gi = m0 + row;
            const float* src;
            if (AMODE == 2) {
                int mm = gi >> 10, rr = gi & 1023;
                src = (mm < L_) ? (A + ((size_t)(mm * BN_TOK + rr)) * K)
                                : (A2 + ((size_t)((mm - L_) * BN_TOK + rr)) * K);
            } else {
                src = A + (size_t)gi * K;
            }
            float4 v = *(const float4*)(src + k0 + c4 * 4);
            if (AMODE == 1) {
                float s = rs[gi];
                v.x *= s * nw[k0 + c4 * 4 + 0];
                v.y *= s * nw[k0 + c4 * 4 + 1];
                v.z *= s * nw[k0 + c4 * 4 + 2];
                v.w *= s * nw[k0 + c4 * 4 + 3];
            }
            As[c4 * 4 + 0][row] = v.x; As[c4 * 4 + 1][row] = v.y;
            As[c4 * 4 + 2][row] = v.z; As[c4 * 4 + 3][row] = v.w;
        }
        #pragma unroll
        for (int r = 0; r < 2; ++r) {
            int q = t + r * 256;
            int kr = q >> 5, c4 = q & 31;
            float4 v = *(const float4*)(Bm + (size_t)(k0 + kr) * Ncols + n0 + c4 * 4);
            *(float4*)&Bs[kr][c4 * 4] = v;
        }
        __syncthreads();
        #pragma unroll
        for (int k = 0; k < 16; ++k) {
            float a[8], b[8];
            *(float4*)&a[0] = *(const float4*)&As[k][ty * 8];
            *(float4*)&a[4] = *(const float4*)&As[k][ty * 8 + 4];
            *(float4*)&b[0] = *(const float4*)&Bs[k][tx * 8];
            *(float4*)&b[4] = *(const float4*)&Bs[k][tx * 8 + 4];
            #pragma unroll
            for (int i = 0; i < 8; ++i)
                #pragma unroll
                for (int j = 0; j < 8; ++j) acc[i][j] = fmaf(a[i], b[j], acc[i][j]);
        }
        __syncthreads();
    }
    #pragma unroll
    for (int i = 0; i < 8; ++i) {
        float* dst = C + (size_t)(m0 + ty * 8 + i) * Ncols + n0 + tx * 8;
        float4 v0 = make_float4(acc[i][0], acc[i][1], acc[i][2], acc[i][3]);
        float4 v1 = make_float4(acc[i][4], acc[i][5], acc[i][6], acc[i][7]);
        *(float4*)dst = v0;
        *(float4*)(dst + 4) = v1;
    }
}

// ---------------------------------------------------------------------------
// Attention kernel: one 64-thread block per (b,n,h) site.
// Fuses: per-head k RMSNorm (knorm_w folded into q), sim, softmax, PV, gating.
// ---------------------------------------------------------------------------
__global__ __launch_bounds__(64) void attn_kernel(
    const float* __restrict__ q,     // [L*1024, 512]
    const float* __restrict__ kv,    // [16*1024, 1024]  (k | v)
    const float* __restrict__ gates, // [L*1024, 8]
    const float* __restrict__ knw,   // [64]
    float* __restrict__ og)          // [L*1024, 512]
{
    const int blk = blockIdx.x;
    const int h = blk & 7, bn = blk >> 3;
    const int t = threadIdx.x;

    __shared__ __align__(16) float qs[8][65];
    __shared__ __align__(16) float ks[16][65];
    __shared__ __align__(16) float vs[16][65];
    __shared__ float ss[8][17];
    __shared__ float kscale[16];
    __shared__ float gs[8];

    const float kw = knw[t];
    #pragma unroll
    for (int l = 0; l < 8; ++l)
        qs[l][t] = q[((size_t)(l * BN_TOK + bn)) * INNER_ + h * DH_ + t] * kw;
    #pragma unroll
    for (int m = 0; m < 16; ++m) {
        const float* kvrow = kv + ((size_t)(m * BN_TOK + bn)) * (2 * INNER_) + h * DH_;
        ks[m][t] = kvrow[t];
        vs[m][t] = kvrow[INNER_ + t];
    }
    if (t < 8) gs[t] = gates[((size_t)(t * BN_TOK + bn)) * H_ + h];
    __syncthreads();

    // k row-rms scales: thread t handles (m = t&15, quarter grp = t>>4)
    {
        int m = t & 15, grp = t >> 4;
        float s = 0.f;
        #pragma unroll
        for (int j = 0; j < 16; ++j) { float v = ks[m][grp * 16 + j]; s = fmaf(v, v, s); }
        s += __shfl_xor(s, 16);
        s += __shfl_xor(s, 32);
        if (grp == 0) kscale[m] = rsqrtf(s * (1.f / DH_) + EPS);
    }
    __syncthreads();

    // sim: 128 (l,m) pairs, 2 per thread
    #pragma unroll
    for (int r = 0; r < 2; ++r) {
        int p = t + r * 64;
        int l = p >> 4, m = p & 15;
        float s = 0.f;
        #pragma unroll
        for (int d = 0; d < 64; ++d) s = fmaf(qs[l][d], ks[m][d], s);
        ss[l][m] = s * kscale[m] * SCALE_;
    }
    __syncthreads();

    // softmax over m (16), one row per thread 0..7
    if (t < 8) {
        float mx = -1e30f;
        #pragma unroll
        for (int m = 0; m < 16; ++m) mx = fmaxf(mx, ss[t][m]);
        float sum = 0.f;
        #pragma unroll
        for (int m = 0; m < 16; ++m) { float e = expf(ss[t][m] - mx); ss[t][m] = e; sum += e; }
        float inv = 1.f / sum;
        #pragma unroll
        for (int m = 0; m < 16; ++m) ss[t][m] *= inv;
    }
    __syncthreads();

    // o[l][d=t] = sum_m attn * v ; apply gate; write
    #pragma unroll
    for (int l = 0; l < 8; ++l) {
        float o = 0.f;
        #pragma unroll
        for (int m = 0; m < 16; ++m) o = fmaf(ss[l][m], vs[m][t], o);
        og[((size_t)(l * BN_TOK + bn)) * INNER_ + h * DH_ + t] = o * gs[l];
    }
}

// ---------------------------------------------------------------------------
extern "C" void kernel_launch(void* const* d_in, const int* in_sizes, int n_in,
                              void* d_out, int out_size, void* d_ws, size_t ws_size,
                              hipStream_t stream)
{
    const float* tokens = (const float*)d_in[0];  // [8,2,512,1024]
    const float* w_net  = (const float*)d_in[1];  // [8,1024,1024]
    const float* b_net  = (const float*)d_in[2];  // [8,1024]
    const float* norm_w = (const float*)d_in[3];  // [1024]
    const float* wq     = (const float*)d_in[4];  // [1024,512]
    const float* wkv    = (const float*)d_in[5];  // [1024,1024]
    const float* knw    = (const float*)d_in[6];  // [64]
    const float* wg     = (const float*)d_in[7];  // [1024,8]
    const float* wout   = (const float*)d_in[8];  // [512,1024]
    float* out = (float*)d_out;                   // [8,2,512,1024]

    float* ws    = (float*)d_ws;
    float* ws_out = ws;                 // 8,388,608 floats  (member linear)
    float* ws_q   = ws + 8388608;       // 4,194,304
    float* ws_kv  = ws + 12582912;      // 16,777,216
    float* ws_og  = ws + 29360128;      // 4,194,304
    float* ws_rs  = ws + 33554432;      // 8,192
    float* ws_g   = ws + 33562624;      // 65,536

    // rs + gates (needs only tokens)
    rs_gates_kernel<<<L_ * BN_TOK, 256, 0, stream>>>(tokens, norm_w, wg, ws_rs, ws_g);
    // member linear: out = tokens @ w_net^T + b_net
    gemm_nt_batched_kernel<<<dim3(8, 8, 8), 256, 0, stream>>>(tokens, w_net, b_net, ws_out);
    // q = (tokens * rs * norm_w) @ wq
    gemm_nn_kernel<1><<<dim3(4, 64), 256, 0, stream>>>(tokens, nullptr, wq, ws_q, ws_rs, norm_w,
                                                       L_ * BN_TOK, INNER_, D_);
    // kv = ctx @ wkv  (ctx gathered from tokens / ws_out)
    gemm_nn_kernel<2><<<dim3(8, 128), 256, 0, stream>>>(tokens, ws_out, wkv, ws_kv, nullptr, nullptr,
                                                        M_ * BN_TOK, 2 * INNER_, D_);
    // attention + gating -> og
    attn_kernel<<<BN_TOK * H_, 64, 0, stream>>>(ws_q, ws_kv, ws_g, knw, ws_og);
    // pooled = og @ wout -> d_out
    gemm_nn_kernel<0><<<dim3(8, 64), 256, 0, stream>>>(ws_og, nullptr, wout, out, nullptr, nullptr,
                                                       L_ * BN_TOK, D_, INNER_);
}

// Round 2
// 213.981 us; speedup vs baseline: 4.2055x; 4.2055x over previous
//
#include <hip/hip_runtime.h>
#include <hip/hip_bf16.h>
#include <math.h>

#define L_ 8
#define B_ 2
#define N_ 512
#define D_ 1024
#define H_ 8
#define DH_ 64
#define INNER_ 512
#define M_ 16
#define BN_TOK 1024            // B_*N_
#define EPS 1.1920928955078125e-07f
#define SCALE_ 0.125f          // DH^-0.5

typedef __attribute__((ext_vector_type(8))) __bf16 bf16x8;
typedef __attribute__((ext_vector_type(4))) __bf16 bf16x4;
typedef __attribute__((ext_vector_type(4))) float f32x4;

// ---------------------------------------------------------------------------
// rs + gates + bf16 conversion kernel: one block per (l,b,n) row.
//   rs[row]    = rsqrt(mean(tokens_row^2) + eps)
//   gates[row] = sigmoid((tokens_row * rs * norm_w) @ wg)   [8 heads] (f32)
//   tok_bf[row][d] = bf16(tokens), tn_bf[row][d] = bf16(tokens*rs*norm_w)
// ---------------------------------------------------------------------------
__global__ __launch_bounds__(256) void rs_gates_kernel(
    const float* __restrict__ tokens, const float* __restrict__ norm_w,
    const float* __restrict__ wg, float* __restrict__ rs_out,
    float* __restrict__ gates_out, __bf16* __restrict__ tok_bf,
    __bf16* __restrict__ tn_bf)
{
    const int row = blockIdx.x;               // l*1024 + b*512 + n
    const float* tr = tokens + (size_t)row * D_;
    const int t = threadIdx.x;
    const int wave = t >> 6, lane = t & 63;
    __shared__ float wsum[4];
    __shared__ float wacc[4][8];

    float ss = 0.f;
    for (int d = t; d < D_; d += 256) { float v = tr[d]; ss = fmaf(v, v, ss); }
    #pragma unroll
    for (int o = 1; o < 64; o <<= 1) ss += __shfl_xor(ss, o);
    if (lane == 0) wsum[wave] = ss;
    __syncthreads();
    const float tot = wsum[0] + wsum[1] + wsum[2] + wsum[3];
    const float rsv = rsqrtf(tot * (1.f / D_) + EPS);
    if (t == 0) rs_out[row] = rsv;

    float acc[8];
    #pragma unroll
    for (int h = 0; h < 8; ++h) acc[h] = 0.f;
    for (int d = t; d < D_; d += 256) {
        float tv = tr[d];
        float v = tv * rsv * norm_w[d];
        tok_bf[(size_t)row * D_ + d] = (__bf16)tv;
        tn_bf[(size_t)row * D_ + d] = (__bf16)v;
        const float* wrow = wg + (size_t)d * H_;
        #pragma unroll
        for (int h = 0; h < 8; ++h) acc[h] = fmaf(v, wrow[h], acc[h]);
    }
    #pragma unroll
    for (int h = 0; h < 8; ++h) {
        #pragma unroll
        for (int o = 1; o < 64; o <<= 1) acc[h] += __shfl_xor(acc[h], o);
    }
    if (lane == 0) {
        #pragma unroll
        for (int h = 0; h < 8; ++h) wacc[wave][h] = acc[h];
    }
    __syncthreads();
    if (t < 8) {
        float g = wacc[0][t] + wacc[1][t] + wacc[2][t] + wacc[3][t];
        gates_out[(size_t)row * H_ + t] = 1.f / (1.f + expf(-g));
    }
}

// ---------------------------------------------------------------------------
// plain f32 -> bf16 convert (same layout), 4 elems/thread
// ---------------------------------------------------------------------------
__global__ __launch_bounds__(256) void convert_bf16_kernel(
    const float* __restrict__ in, __bf16* __restrict__ out)
{
    const int i = blockIdx.x * 256 + threadIdx.x;
    float4 v = ((const float4*)in)[i];
    bf16x4 o;
    o.x = (__bf16)v.x; o.y = (__bf16)v.y; o.z = (__bf16)v.z; o.w = (__bf16)v.w;
    *(bf16x4*)(out + (size_t)i * 4) = o;
}

// ---------------------------------------------------------------------------
// transpose + convert: in f32 [R][C] -> out bf16 [C][R]. 32x32 tiles.
// ---------------------------------------------------------------------------
__global__ __launch_bounds__(256) void transpose_convert_kernel(
    const float* __restrict__ in, __bf16* __restrict__ out, int R, int C)
{
    __shared__ float tile[32][33];
    const int bx = blockIdx.x;     // C tile
    const int by = blockIdx.y;     // R tile
    const int x = threadIdx.x & 31, y = threadIdx.x >> 5;   // 32 x 8
    #pragma unroll
    for (int r = 0; r < 4; ++r)
        tile[y + r * 8][x] = in[(size_t)(by * 32 + y + r * 8) * C + bx * 32 + x];
    __syncthreads();
    #pragma unroll
    for (int r = 0; r < 4; ++r)
        out[(size_t)(bx * 32 + y + r * 8) * R + by * 32 + x] = (__bf16)tile[x][y + r * 8];
}

// ---------------------------------------------------------------------------
// bf16 MFMA GEMM, C = A @ Bt^T.  A [M][K] bf16 row-major, Bt [N][K] bf16
// row-major.  128x128 tile, BK=32, 256 threads (4 waves 2x2 of 64x64),
// 16x16x32 MFMA, global_load_lds width-16 staging (m97 structure).
// MODE: 0 = f32 out; 1 = bf16 out; 2 = member linear (per-l Bt, +bias,
// bf16 out); 3 = kv (A row-gather across A/A2 at 8192, bf16 out).
// ---------------------------------------------------------------------------
template <int MODE>
__global__ __launch_bounds__(256) void gemm_bt_mfma(
    const __bf16* __restrict__ A, const __bf16* __restrict__ A2,
    const __bf16* __restrict__ Bt, const float* __restrict__ bias,
    void* __restrict__ Cout, int Mrows, int Ncols, int K)
{
    __shared__ __align__(16) __bf16 As[128 * 32];
    __shared__ __align__(16) __bf16 Bs[128 * 32];
    const int t = threadIdx.x;
    const int w = t >> 6, lane = t & 63;
    const int m0 = blockIdx.y * 128, n0 = blockIdx.x * 128;
    const int wm = w >> 1, wn = w & 1;

    const __bf16* Ab;
    if (MODE == 3)
        Ab = (m0 < 8192) ? (A + (size_t)m0 * K) : (A2 + (size_t)(m0 - 8192) * K);
    else
        Ab = A + (size_t)m0 * K;
    const __bf16* Btb = Bt
        + ((MODE == 2) ? ((size_t)(m0 >> 10) * (size_t)Ncols * K) : (size_t)0)
        + (size_t)n0 * K;

    // staging geometry: wave w covers rows [w*32, w*32+32) via 2 loads of
    // 16 rows; lane l -> row = l>>2, 16B chunk = l&3 within the 64B row.
    const int srow = w * 32 + (lane >> 2);
    const int scol = (lane & 3) * 8;

    f32x4 acc[4][4];
    #pragma unroll
    for (int i = 0; i < 4; ++i)
        #pragma unroll
        for (int j = 0; j < 4; ++j)
            acc[i][j] = (f32x4){0.f, 0.f, 0.f, 0.f};

    for (int k0 = 0; k0 < K; k0 += 32) {
        __builtin_amdgcn_global_load_lds(
            (const __attribute__((address_space(1))) void*)(Ab + (size_t)srow * K + k0 + scol),
            (__attribute__((address_space(3))) void*)(&As[(w * 32) * 32]), 16, 0, 0);
        __builtin_amdgcn_global_load_lds(
            (const __attribute__((address_space(1))) void*)(Ab + (size_t)(srow + 16) * K + k0 + scol),
            (__attribute__((address_space(3))) void*)(&As[(w * 32 + 16) * 32]), 16, 0, 0);
        __builtin_amdgcn_global_load_lds(
            (const __attribute__((address_space(1))) void*)(Btb + (size_t)srow * K + k0 + scol),
            (__attribute__((address_space(3))) void*)(&Bs[(w * 32) * 32]), 16, 0, 0);
        __builtin_amdgcn_global_load_lds(
            (const __attribute__((address_space(1))) void*)(Btb + (size_t)(srow + 16) * K + k0 + scol),
            (__attribute__((address_space(3))) void*)(&Bs[(w * 32 + 16) * 32]), 16, 0, 0);
        __syncthreads();

        bf16x8 af[4], bfr[4];
        #pragma unroll
        for (int i = 0; i < 4; ++i) {
            const int arow = wm * 64 + i * 16 + (lane & 15);
            af[i] = *(const bf16x8*)(&As[arow * 32 + (lane >> 4) * 8]);
            const int bcol = wn * 64 + i * 16 + (lane & 15);
            bfr[i] = *(const bf16x8*)(&Bs[bcol * 32 + (lane >> 4) * 8]);
        }
        #pragma unroll
        for (int i = 0; i < 4; ++i)
            #pragma unroll
            for (int j = 0; j < 4; ++j)
                acc[i][j] = __builtin_amdgcn_mfma_f32_16x16x32_bf16(af[i], bfr[j], acc[i][j], 0, 0, 0);
        __syncthreads();
    }

    // epilogue: D mapping col=lane&15, row=(lane>>4)*4+reg
    #pragma unroll
    for (int i = 0; i < 4; ++i) {
        const int r0 = m0 + wm * 64 + i * 16 + ((lane >> 4) << 2);
        #pragma unroll
        for (int j = 0; j < 4; ++j) {
            const int col = n0 + wn * 64 + j * 16 + (lane & 15);
            float badd = 0.f;
            if (MODE == 2) badd = bias[(size_t)(m0 >> 10) * Ncols + col];
            #pragma unroll
            for (int r = 0; r < 4; ++r) {
                float v = acc[i][j][r] + badd;
                if (MODE == 0)
                    ((float*)Cout)[(size_t)(r0 + r) * Ncols + col] = v;
                else
                    ((__bf16*)Cout)[(size_t)(r0 + r) * Ncols + col] = (__bf16)v;
            }
        }
    }
}

// ---------------------------------------------------------------------------
// Attention kernel: one 64-thread block per (b,n,h) site (bf16 in/out).
// ---------------------------------------------------------------------------
__global__ __launch_bounds__(64) void attn_kernel(
    const __bf16* __restrict__ q,     // [8192, 512]
    const __bf16* __restrict__ kv,    // [16384, 1024]  (k | v)
    const float* __restrict__ gates,  // [8192, 8]
    const float* __restrict__ knw,    // [64]
    __bf16* __restrict__ og)          // [8192, 512]
{
    const int blk = blockIdx.x;
    const int h = blk & 7, bn = blk >> 3;
    const int t = threadIdx.x;

    __shared__ __align__(16) float qs[8][65];
    __shared__ __align__(16) float ks[16][65];
    __shared__ __align__(16) float vs[16][65];
    __shared__ float ss[8][17];
    __shared__ float kscale[16];
    __shared__ float gs[8];

    const float kw = knw[t];
    #pragma unroll
    for (int l = 0; l < 8; ++l)
        qs[l][t] = (float)q[((size_t)(l * BN_TOK + bn)) * INNER_ + h * DH_ + t] * kw;
    #pragma unroll
    for (int m = 0; m < 16; ++m) {
        const __bf16* kvrow = kv + ((size_t)(m * BN_TOK + bn)) * (2 * INNER_) + h * DH_;
        ks[m][t] = (float)kvrow[t];
        vs[m][t] = (float)kvrow[INNER_ + t];
    }
    if (t < 8) gs[t] = gates[((size_t)(t * BN_TOK + bn)) * H_ + h];
    __syncthreads();

    {
        int m = t & 15, grp = t >> 4;
        float s = 0.f;
        #pragma unroll
        for (int j = 0; j < 16; ++j) { float v = ks[m][grp * 16 + j]; s = fmaf(v, v, s); }
        s += __shfl_xor(s, 16);
        s += __shfl_xor(s, 32);
        if (grp == 0) kscale[m] = rsqrtf(s * (1.f / DH_) + EPS);
    }
    __syncthreads();

    #pragma unroll
    for (int r = 0; r < 2; ++r) {
        int p = t + r * 64;
        int l = p >> 4, m = p & 15;
        float s = 0.f;
        #pragma unroll
        for (int d = 0; d < 64; ++d) s = fmaf(qs[l][d], ks[m][d], s);
        ss[l][m] = s * kscale[m] * SCALE_;
    }
    __syncthreads();

    if (t < 8) {
        float mx = -1e30f;
        #pragma unroll
        for (int m = 0; m < 16; ++m) mx = fmaxf(mx, ss[t][m]);
        float sum = 0.f;
        #pragma unroll
        for (int m = 0; m < 16; ++m) { float e = expf(ss[t][m] - mx); ss[t][m] = e; sum += e; }
        float inv = 1.f / sum;
        #pragma unroll
        for (int m = 0; m < 16; ++m) ss[t][m] *= inv;
    }
    __syncthreads();

    #pragma unroll
    for (int l = 0; l < 8; ++l) {
        float o = 0.f;
        #pragma unroll
        for (int m = 0; m < 16; ++m) o = fmaf(ss[l][m], vs[m][t], o);
        og[((size_t)(l * BN_TOK + bn)) * INNER_ + h * DH_ + t] = (__bf16)(o * gs[l]);
    }
}

// ---------------------------------------------------------------------------
extern "C" void kernel_launch(void* const* d_in, const int* in_sizes, int n_in,
                              void* d_out, int out_size, void* d_ws, size_t ws_size,
                              hipStream_t stream)
{
    const float* tokens = (const float*)d_in[0];  // [8,2,512,1024]
    const float* w_net  = (const float*)d_in[1];  // [8,1024,1024]
    const float* b_net  = (const float*)d_in[2];  // [8,1024]
    const float* norm_w = (const float*)d_in[3];  // [1024]
    const float* wq     = (const float*)d_in[4];  // [1024,512]
    const float* wkv    = (const float*)d_in[5];  // [1024,1024]
    const float* knw    = (const float*)d_in[6];  // [64]
    const float* wg     = (const float*)d_in[7];  // [1024,8]
    const float* wout   = (const float*)d_in[8];  // [512,1024]
    float* out = (float*)d_out;                   // [8,2,512,1024]

    char* ws = (char*)d_ws;
    __bf16* tok_bf  = (__bf16*)(ws);                         // 16,777,216 B
    __bf16* tn_bf   = (__bf16*)(ws + 16777216);              // 16,777,216
    __bf16* out_bf  = (__bf16*)(ws + 33554432);              // 16,777,216
    __bf16* q_bf    = (__bf16*)(ws + 50331648);              //  8,388,608
    __bf16* kv_bf   = (__bf16*)(ws + 58720256);              // 33,554,432
    __bf16* og_bf   = (__bf16*)(ws + 92274688);              //  8,388,608
    __bf16* wnet_bf = (__bf16*)(ws + 100663296);             // 16,777,216
    __bf16* wqt_bf  = (__bf16*)(ws + 117440512);             //  1,048,576
    __bf16* wkvt_bf = (__bf16*)(ws + 118489088);             //  2,097,152
    __bf16* woutt_bf= (__bf16*)(ws + 120586240);             //  1,048,576
    float*  ws_rs   = (float*)(ws + 121634816);              //     32,768
    float*  ws_g    = (float*)(ws + 121667584);              //    262,144

    // rs + gates + bf16 token/tn conversion
    rs_gates_kernel<<<L_ * BN_TOK, 256, 0, stream>>>(tokens, norm_w, wg, ws_rs, ws_g, tok_bf, tn_bf);
    // weight conversions
    convert_bf16_kernel<<<8192, 256, 0, stream>>>(w_net, wnet_bf);                       // 8M elems
    transpose_convert_kernel<<<dim3(16, 32), 256, 0, stream>>>(wq, wqt_bf, 1024, 512);
    transpose_convert_kernel<<<dim3(32, 32), 256, 0, stream>>>(wkv, wkvt_bf, 1024, 1024);
    transpose_convert_kernel<<<dim3(32, 16), 256, 0, stream>>>(wout, woutt_bf, 512, 1024);

    // member linear: out = tokens @ w_net^T + b_net  (w_net rows are Bt rows)
    gemm_bt_mfma<2><<<dim3(8, 64), 256, 0, stream>>>(tok_bf, nullptr, wnet_bf, b_net,
                                                     (void*)out_bf, 8192, 1024, 1024);
    // q = tn @ wq
    gemm_bt_mfma<1><<<dim3(4, 64), 256, 0, stream>>>(tn_bf, nullptr, wqt_bf, nullptr,
                                                     (void*)q_bf, 8192, 512, 1024);
    // kv = ctx @ wkv   (ctx rows gathered: [0,8192) tokens, [8192,16384) out)
    gemm_bt_mfma<3><<<dim3(8, 128), 256, 0, stream>>>(tok_bf, out_bf, wkvt_bf, nullptr,
                                                      (void*)kv_bf, 16384, 1024, 1024);
    // attention + gating
    attn_kernel<<<BN_TOK * H_, 64, 0, stream>>>(q_bf, kv_bf, ws_g, knw, og_bf);
    // pooled = og @ wout -> d_out (f32)
    gemm_bt_mfma<0><<<dim3(8, 64), 256, 0, stream>>>(og_bf, nullptr, woutt_bf, nullptr,
                                                     (void*)out, 8192, 1024, 512);
}

// Round 3
// 197.979 us; speedup vs baseline: 4.5454x; 1.0808x over previous
//
#include <hip/hip_runtime.h>
#include <hip/hip_bf16.h>
#include <math.h>

#define L_ 8
#define B_ 2
#define N_ 512
#define D_ 1024
#define H_ 8
#define DH_ 64
#define INNER_ 512
#define M_ 16
#define BN_TOK 1024            // B_*N_
#define EPS 1.1920928955078125e-07f
#define SCALE_ 0.125f          // DH^-0.5

typedef __attribute__((ext_vector_type(8))) __bf16 bf16x8;
typedef __attribute__((ext_vector_type(4))) __bf16 bf16x4;
typedef __attribute__((ext_vector_type(4))) float f32x4;

// ---------------------------------------------------------------------------
// rs + gates + bf16 conversion kernel: one block per (l,b,n) row.
// ---------------------------------------------------------------------------
__global__ __launch_bounds__(256) void rs_gates_kernel(
    const float* __restrict__ tokens, const float* __restrict__ norm_w,
    const float* __restrict__ wg, float* __restrict__ rs_out,
    float* __restrict__ gates_out, __bf16* __restrict__ tok_bf,
    __bf16* __restrict__ tn_bf)
{
    const int row = blockIdx.x;               // l*1024 + b*512 + n
    const float* tr = tokens + (size_t)row * D_;
    const int t = threadIdx.x;
    const int wave = t >> 6, lane = t & 63;
    __shared__ float wsum[4];
    __shared__ float wacc[4][8];

    float ss = 0.f;
    for (int d = t; d < D_; d += 256) { float v = tr[d]; ss = fmaf(v, v, ss); }
    #pragma unroll
    for (int o = 1; o < 64; o <<= 1) ss += __shfl_xor(ss, o);
    if (lane == 0) wsum[wave] = ss;
    __syncthreads();
    const float tot = wsum[0] + wsum[1] + wsum[2] + wsum[3];
    const float rsv = rsqrtf(tot * (1.f / D_) + EPS);
    if (t == 0) rs_out[row] = rsv;

    float acc[8];
    #pragma unroll
    for (int h = 0; h < 8; ++h) acc[h] = 0.f;
    for (int d = t; d < D_; d += 256) {
        float tv = tr[d];
        float v = tv * rsv * norm_w[d];
        tok_bf[(size_t)row * D_ + d] = (__bf16)tv;
        tn_bf[(size_t)row * D_ + d] = (__bf16)v;
        const float* wrow = wg + (size_t)d * H_;
        #pragma unroll
        for (int h = 0; h < 8; ++h) acc[h] = fmaf(v, wrow[h], acc[h]);
    }
    #pragma unroll
    for (int h = 0; h < 8; ++h) {
        #pragma unroll
        for (int o = 1; o < 64; o <<= 1) acc[h] += __shfl_xor(acc[h], o);
    }
    if (lane == 0) {
        #pragma unroll
        for (int h = 0; h < 8; ++h) wacc[wave][h] = acc[h];
    }
    __syncthreads();
    if (t < 8) {
        float g = wacc[0][t] + wacc[1][t] + wacc[2][t] + wacc[3][t];
        gates_out[(size_t)row * H_ + t] = 1.f / (1.f + expf(-g));
    }
}

// ---------------------------------------------------------------------------
__global__ __launch_bounds__(256) void convert_bf16_kernel(
    const float* __restrict__ in, __bf16* __restrict__ out)
{
    const int i = blockIdx.x * 256 + threadIdx.x;
    float4 v = ((const float4*)in)[i];
    bf16x4 o;
    o.x = (__bf16)v.x; o.y = (__bf16)v.y; o.z = (__bf16)v.z; o.w = (__bf16)v.w;
    *(bf16x4*)(out + (size_t)i * 4) = o;
}

// ---------------------------------------------------------------------------
__global__ __launch_bounds__(256) void transpose_convert_kernel(
    const float* __restrict__ in, __bf16* __restrict__ out, int R, int C)
{
    __shared__ float tile[32][33];
    const int bx = blockIdx.x;     // C tile
    const int by = blockIdx.y;     // R tile
    const int x = threadIdx.x & 31, y = threadIdx.x >> 5;   // 32 x 8
    #pragma unroll
    for (int r = 0; r < 4; ++r)
        tile[y + r * 8][x] = in[(size_t)(by * 32 + y + r * 8) * C + bx * 32 + x];
    __syncthreads();
    #pragma unroll
    for (int r = 0; r < 4; ++r)
        out[(size_t)(bx * 32 + y + r * 8) * R + by * 32 + x] = (__bf16)tile[x][y + r * 8];
}

// ---------------------------------------------------------------------------
// bf16 MFMA GEMM, C = A @ Bt^T.  A [M][K] bf16 row-major, Bt [N][K] bf16
// row-major.  128x128 tile, BK=32, 256 threads (4 waves 2x2 of 64x64),
// 16x16x32 MFMA, global_load_lds width-16 staging (m97 structure).
// 1D grid with XCD-aware decode (T1): blocks sharing an A row-panel all
// get bid % 8 == same value -> same XCD -> A panel fetched once per XCD.
// Requires nty % 8 == 0 and grid == ntx*nty (bijective).
// MODE: 0 = f32 out; 1 = bf16 out; 2 = member linear (per-l Bt, +bias,
// bf16 out); 3 = kv (A row-gather across A/A2 at 8192, bf16 out).
// ---------------------------------------------------------------------------
template <int MODE>
__global__ __launch_bounds__(256) void gemm_bt_mfma(
    const __bf16* __restrict__ A, const __bf16* __restrict__ A2,
    const __bf16* __restrict__ Bt, const float* __restrict__ bias,
    void* __restrict__ Cout, int Ncols, int K, int ntx, int nty)
{
    __shared__ __align__(16) __bf16 As[128 * 32];
    __shared__ __align__(16) __bf16 Bs[128 * 32];
    const int t = threadIdx.x;
    const int w = t >> 6, lane = t & 63;

    // XCD-aware tile decode
    const int bid = blockIdx.x;
    const int c = bid & 7;
    const int s = bid >> 3;
    const int sq = s / ntx;
    const int bty = c * (nty >> 3) + sq;
    const int btx = s - sq * ntx;
    const int m0 = bty * 128, n0 = btx * 128;
    const int wm = w >> 1, wn = w & 1;

    const __bf16* Ab;
    if (MODE == 3)
        Ab = (m0 < 8192) ? (A + (size_t)m0 * K) : (A2 + (size_t)(m0 - 8192) * K);
    else
        Ab = A + (size_t)m0 * K;
    const __bf16* Btb = Bt
        + ((MODE == 2) ? ((size_t)(m0 >> 10) * (size_t)Ncols * K) : (size_t)0)
        + (size_t)n0 * K;

    const int srow = w * 32 + (lane >> 2);
    const int scol = (lane & 3) * 8;

    f32x4 acc[4][4];
    #pragma unroll
    for (int i = 0; i < 4; ++i)
        #pragma unroll
        for (int j = 0; j < 4; ++j)
            acc[i][j] = (f32x4){0.f, 0.f, 0.f, 0.f};

    for (int k0 = 0; k0 < K; k0 += 32) {
        __builtin_amdgcn_global_load_lds(
            (const __attribute__((address_space(1))) void*)(Ab + (size_t)srow * K + k0 + scol),
            (__attribute__((address_space(3))) void*)(&As[(w * 32) * 32]), 16, 0, 0);
        __builtin_amdgcn_global_load_lds(
            (const __attribute__((address_space(1))) void*)(Ab + (size_t)(srow + 16) * K + k0 + scol),
            (__attribute__((address_space(3))) void*)(&As[(w * 32 + 16) * 32]), 16, 0, 0);
        __builtin_amdgcn_global_load_lds(
            (const __attribute__((address_space(1))) void*)(Btb + (size_t)srow * K + k0 + scol),
            (__attribute__((address_space(3))) void*)(&Bs[(w * 32) * 32]), 16, 0, 0);
        __builtin_amdgcn_global_load_lds(
            (const __attribute__((address_space(1))) void*)(Btb + (size_t)(srow + 16) * K + k0 + scol),
            (__attribute__((address_space(3))) void*)(&Bs[(w * 32 + 16) * 32]), 16, 0, 0);
        __syncthreads();

        bf16x8 af[4], bfr[4];
        #pragma unroll
        for (int i = 0; i < 4; ++i) {
            const int arow = wm * 64 + i * 16 + (lane & 15);
            af[i] = *(const bf16x8*)(&As[arow * 32 + (lane >> 4) * 8]);
            const int bcol = wn * 64 + i * 16 + (lane & 15);
            bfr[i] = *(const bf16x8*)(&Bs[bcol * 32 + (lane >> 4) * 8]);
        }
        #pragma unroll
        for (int i = 0; i < 4; ++i)
            #pragma unroll
            for (int j = 0; j < 4; ++j)
                acc[i][j] = __builtin_amdgcn_mfma_f32_16x16x32_bf16(af[i], bfr[j], acc[i][j], 0, 0, 0);
        __syncthreads();
    }

    #pragma unroll
    for (int i = 0; i < 4; ++i) {
        const int r0 = m0 + wm * 64 + i * 16 + ((lane >> 4) << 2);
        #pragma unroll
        for (int j = 0; j < 4; ++j) {
            const int col = n0 + wn * 64 + j * 16 + (lane & 15);
            float badd = 0.f;
            if (MODE == 2) badd = bias[(size_t)(m0 >> 10) * Ncols + col];
            #pragma unroll
            for (int r = 0; r < 4; ++r) {
                float v = acc[i][j][r] + badd;
                if (MODE == 0)
                    ((float*)Cout)[(size_t)(r0 + r) * Ncols + col] = v;
                else
                    ((__bf16*)Cout)[(size_t)(r0 + r) * Ncols + col] = (__bf16)v;
            }
        }
    }
}

// ---------------------------------------------------------------------------
// Attention kernel: one 64-thread block per (b,n,h) site (bf16 in/out).
// XCD-aware decode: the 8 h-blocks of one bn site share 16 kv rows, so
// give each XCD a contiguous band of 128 bn sites.
// ---------------------------------------------------------------------------
__global__ __launch_bounds__(64) void attn_kernel(
    const __bf16* __restrict__ q,     // [8192, 512]
    const __bf16* __restrict__ kv,    // [16384, 1024]  (k | v)
    const float* __restrict__ gates,  // [8192, 8]
    const float* __restrict__ knw,    // [64]
    __bf16* __restrict__ og)          // [8192, 512]
{
    const int bid = blockIdx.x;
    const int c = bid & 7;
    const int s = bid >> 3;
    const int bn = c * 128 + (s >> 3);
    const int h = s & 7;
    const int t = threadIdx.x;

    __shared__ __align__(16) float qs[8][65];
    __shared__ __align__(16) float ks[16][65];
    __shared__ __align__(16) float vs[16][65];
    __shared__ float ss[8][17];
    __shared__ float kscale[16];
    __shared__ float gs[8];

    const float kw = knw[t];
    #pragma unroll
    for (int l = 0; l < 8; ++l)
        qs[l][t] = (float)q[((size_t)(l * BN_TOK + bn)) * INNER_ + h * DH_ + t] * kw;
    #pragma unroll
    for (int m = 0; m < 16; ++m) {
        const __bf16* kvrow = kv + ((size_t)(m * BN_TOK + bn)) * (2 * INNER_) + h * DH_;
        ks[m][t] = (float)kvrow[t];
        vs[m][t] = (float)kvrow[INNER_ + t];
    }
    if (t < 8) gs[t] = gates[((size_t)(t * BN_TOK + bn)) * H_ + h];
    __syncthreads();

    {
        int m = t & 15, grp = t >> 4;
        float s2 = 0.f;
        #pragma unroll
        for (int j = 0; j < 16; ++j) { float v = ks[m][grp * 16 + j]; s2 = fmaf(v, v, s2); }
        s2 += __shfl_xor(s2, 16);
        s2 += __shfl_xor(s2, 32);
        if (grp == 0) kscale[m] = rsqrtf(s2 * (1.f / DH_) + EPS);
    }
    __syncthreads();

    #pragma unroll
    for (int r = 0; r < 2; ++r) {
        int p = t + r * 64;
        int l = p >> 4, m = p & 15;
        float s2 = 0.f;
        #pragma unroll
        for (int d = 0; d < 64; ++d) s2 = fmaf(qs[l][d], ks[m][d], s2);
        ss[l][m] = s2 * kscale[m] * SCALE_;
    }
    __syncthreads();

    if (t < 8) {
        float mx = -1e30f;
        #pragma unroll
        for (int m = 0; m < 16; ++m) mx = fmaxf(mx, ss[t][m]);
        float sum = 0.f;
        #pragma unroll
        for (int m = 0; m < 16; ++m) { float e = expf(ss[t][m] - mx); ss[t][m] = e; sum += e; }
        float inv = 1.f / sum;
        #pragma unroll
        for (int m = 0; m < 16; ++m) ss[t][m] *= inv;
    }
    __syncthreads();

    #pragma unroll
    for (int l = 0; l < 8; ++l) {
        float o = 0.f;
        #pragma unroll
        for (int m = 0; m < 16; ++m) o = fmaf(ss[l][m], vs[m][t], o);
        og[((size_t)(l * BN_TOK + bn)) * INNER_ + h * DH_ + t] = (__bf16)(o * gs[l]);
    }
}

// ---------------------------------------------------------------------------
extern "C" void kernel_launch(void* const* d_in, const int* in_sizes, int n_in,
                              void* d_out, int out_size, void* d_ws, size_t ws_size,
                              hipStream_t stream)
{
    const float* tokens = (const float*)d_in[0];  // [8,2,512,1024]
    const float* w_net  = (const float*)d_in[1];  // [8,1024,1024]
    const float* b_net  = (const float*)d_in[2];  // [8,1024]
    const float* norm_w = (const float*)d_in[3];  // [1024]
    const float* wq     = (const float*)d_in[4];  // [1024,512]
    const float* wkv    = (const float*)d_in[5];  // [1024,1024]
    const float* knw    = (const float*)d_in[6];  // [64]
    const float* wg     = (const float*)d_in[7];  // [1024,8]
    const float* wout   = (const float*)d_in[8];  // [512,1024]
    float* out = (float*)d_out;                   // [8,2,512,1024]

    char* ws = (char*)d_ws;
    __bf16* tok_bf  = (__bf16*)(ws);                         // 16,777,216 B
    __bf16* tn_bf   = (__bf16*)(ws + 16777216);              // 16,777,216
    __bf16* out_bf  = (__bf16*)(ws + 33554432);              // 16,777,216
    __bf16* q_bf    = (__bf16*)(ws + 50331648);              //  8,388,608
    __bf16* kv_bf   = (__bf16*)(ws + 58720256);              // 33,554,432
    __bf16* og_bf   = (__bf16*)(ws + 92274688);              //  8,388,608
    __bf16* wnet_bf = (__bf16*)(ws + 100663296);             // 16,777,216
    __bf16* wqt_bf  = (__bf16*)(ws + 117440512);             //  1,048,576
    __bf16* wkvt_bf = (__bf16*)(ws + 118489088);             //  2,097,152
    __bf16* woutt_bf= (__bf16*)(ws + 120586240);             //  1,048,576
    float*  ws_rs   = (float*)(ws + 121634816);              //     32,768
    float*  ws_g    = (float*)(ws + 121667584);              //    262,144

    rs_gates_kernel<<<L_ * BN_TOK, 256, 0, stream>>>(tokens, norm_w, wg, ws_rs, ws_g, tok_bf, tn_bf);
    convert_bf16_kernel<<<8192, 256, 0, stream>>>(w_net, wnet_bf);
    transpose_convert_kernel<<<dim3(16, 32), 256, 0, stream>>>(wq, wqt_bf, 1024, 512);
    transpose_convert_kernel<<<dim3(32, 32), 256, 0, stream>>>(wkv, wkvt_bf, 1024, 1024);
    transpose_convert_kernel<<<dim3(32, 16), 256, 0, stream>>>(wout, woutt_bf, 512, 1024);

    // member linear: out = tokens @ w_net^T + b_net   (ntx=8, nty=64; XCD c == l)
    gemm_bt_mfma<2><<<512, 256, 0, stream>>>(tok_bf, nullptr, wnet_bf, b_net,
                                             (void*)out_bf, 1024, 1024, 8, 64);
    // q = tn @ wq   (ntx=4, nty=64)
    gemm_bt_mfma<1><<<256, 256, 0, stream>>>(tn_bf, nullptr, wqt_bf, nullptr,
                                             (void*)q_bf, 512, 1024, 4, 64);
    // kv = ctx @ wkv   (ntx=8, nty=128)
    gemm_bt_mfma<3><<<1024, 256, 0, stream>>>(tok_bf, out_bf, wkvt_bf, nullptr,
                                              (void*)kv_bf, 1024, 1024, 8, 128);
    // attention + gating
    attn_kernel<<<BN_TOK * H_, 64, 0, stream>>>(q_bf, kv_bf, ws_g, knw, og_bf);
    // pooled = og @ wout -> d_out (f32)   (ntx=8, nty=64)
    gemm_bt_mfma<0><<<512, 256, 0, stream>>>(og_bf, nullptr, woutt_bf, nullptr,
                                             (void*)out, 1024, 512, 8, 64);
}